// Round 1
// baseline (550.590 us; speedup 1.0000x reference)
//
#include <hip/hip_runtime.h>

typedef unsigned long long u64;
typedef unsigned int u32;

#define BATCH 2048
#define DIM   64
#define QSIZE 131072
#define HALFB (BATCH / 2)

#define BM 128
#define BN 128
#define NTILES (QSIZE / BN)   // 1024
#define NSPLIT 64             // n-dimension grid split; each block does NTILES/NSPLIT = 16 tiles

// Physical float offset within one [k] row of the LDS tile for logical column n.
// f4-group permutation c -> ((c&1)<<4)|(c>>1) makes the compute-side b128 reads
// (16 lanes, 8-float stride) land contiguous -> 2-way bank aliasing (free).
__device__ __forceinline__ int swz(int n) {
  int c = n >> 2;
  int p = ((c & 1) << 4) | (c >> 1);
  return p * 4 + (n & 3);
}

__global__ __launch_bounds__(256, 2) void sim_argmax_kernel(
    const float* __restrict__ x, const float* __restrict__ q,
    u64* __restrict__ ws)
{
  __shared__ float As[DIM * BM];  // 32 KB, [k][swizzled m]
  __shared__ float Bs[DIM * BN];  // 32 KB, [k][swizzled n]

  const int tid  = threadIdx.x;
  const int tn   = tid & 15;
  const int tm   = tid >> 4;
  const int mblk = blockIdx.x * BM;

  // Stage A tile (x rows mblk..mblk+127), transposed into [k][m].
  {
    const int c4 = tid & 15;  // which float4 along k
    const int r0 = tid >> 4;  // row
    for (int r = r0; r < BM; r += 16) {
      float4 v = ((const float4*)(x + (size_t)(mblk + r) * DIM))[c4];
      int k = c4 * 4;
      int co = swz(r);
      As[(k + 0) * BM + co] = v.x;
      As[(k + 1) * BM + co] = v.y;
      As[(k + 2) * BM + co] = v.z;
      As[(k + 3) * BM + co] = v.w;
    }
  }

  float best[8];
  u32   bidx[8];
#pragma unroll
  for (int i = 0; i < 8; ++i) { best[i] = -3.4e38f; bidx[i] = 0; }

  // Thread's fragment offsets (already swizzle-resolved; see swz()):
  // logical m rows tm*8..tm*8+7 live at phys floats [tm*4..tm*4+3] and [64+tm*4..64+tm*4+3].
  const int a0off = tm * 4;
  const int a1off = 64 + tm * 4;
  const int b0off = tn * 4;
  const int b1off = 64 + tn * 4;

  for (int nt = blockIdx.y; nt < NTILES; nt += NSPLIT) {
    const int nbase = nt * BN;
    __syncthreads();  // previous iteration's reads done before Bs overwrite
    {
      const int c4 = tid & 15;
      const int r0 = tid >> 4;
      for (int r = r0; r < BN; r += 16) {
        float4 v = ((const float4*)(q + (size_t)(nbase + r) * DIM))[c4];
        int k = c4 * 4;
        int co = swz(r);
        Bs[(k + 0) * BN + co] = v.x;
        Bs[(k + 1) * BN + co] = v.y;
        Bs[(k + 2) * BN + co] = v.z;
        Bs[(k + 3) * BN + co] = v.w;
      }
    }
    __syncthreads();

    float acc[8][8];
#pragma unroll
    for (int i = 0; i < 8; ++i)
#pragma unroll
      for (int j = 0; j < 8; ++j) acc[i][j] = 0.f;

#pragma unroll 8
    for (int k = 0; k < DIM; ++k) {
      const float* Ar = As + k * BM;
      const float* Br = Bs + k * BN;
      float4 A0 = *(const float4*)(Ar + a0off);
      float4 A1 = *(const float4*)(Ar + a1off);
      float4 B0 = *(const float4*)(Br + b0off);
      float4 B1 = *(const float4*)(Br + b1off);
      float a[8] = {A0.x, A0.y, A0.z, A0.w, A1.x, A1.y, A1.z, A1.w};
      float b[8] = {B0.x, B0.y, B0.z, B0.w, B1.x, B1.y, B1.z, B1.w};
#pragma unroll
      for (int i = 0; i < 8; ++i)
#pragma unroll
        for (int j = 0; j < 8; ++j)
          acc[i][j] = fmaf(a[i], b[j], acc[i][j]);
    }

    // Running per-thread argmax. j scans ascending global index and uses strict '>',
    // so the smallest index wins ties (matches jnp.argmax).
#pragma unroll
    for (int i = 0; i < 8; ++i) {
#pragma unroll
      for (int j = 0; j < 8; ++j) {
        if (acc[i][j] > best[i]) { best[i] = acc[i][j]; bidx[i] = (u32)(nbase + tn * 8 + j); }
      }
    }
  }

  // Block-level reduce: pack (monotone float key << 32) | ~idx, so max() prefers
  // higher sim, then smaller index on exact ties.
  __syncthreads();
  u64* red = (u64*)As;  // 128*16*8 = 16 KB, aliases As (no longer needed)
#pragma unroll
  for (int i = 0; i < 8; ++i) {
    u32 fb = __float_as_uint(best[i]);
    fb = (fb & 0x80000000u) ? ~fb : (fb | 0x80000000u);
    red[(tm * 8 + i) * 16 + tn] = ((u64)fb << 32) | (u32)(~bidx[i]);
  }
  __syncthreads();
  if (tid < BM) {
    u64 mx = 0;
    for (int j = 0; j < 16; ++j) {
      u64 v = red[tid * 16 + j];
      mx = (v > mx) ? v : mx;
    }
    atomicMax(&ws[mblk + tid], mx);
  }
}

// new_queue: copy queue, substituting rows [ptr, ptr+1024) mod SIZE from x. One pass, no race.
__global__ void copy_update_kernel(const float* __restrict__ x,
                                   const float* __restrict__ q,
                                   const int* __restrict__ ptr_in,
                                   float* __restrict__ newq)
{
  int i = blockIdx.x * blockDim.x + threadIdx.x;  // float4 index, total QSIZE*DIM/4
  int r = i >> 4;                                 // queue row
  int c = i & 15;                                 // float4 within row
  int ptr = *ptr_in;
  u32 off = (u32)(r - ptr) & (QSIZE - 1);
  float4 v = (off < HALFB) ? ((const float4*)x)[off * 16 + c]
                           : ((const float4*)q)[i];
  ((float4*)newq)[i] = v;
}

__global__ void gather_kernel(const float* __restrict__ q,
                              const u64* __restrict__ ws,
                              const int* __restrict__ ptr_in,
                              float* __restrict__ nn,
                              float* __restrict__ ptr_out)
{
  int t = blockIdx.x * blockDim.x + threadIdx.x;  // 0 .. BATCH*DIM-1
  int b = t >> 6;
  int d = t & 63;
  u32 qidx = ~(u32)(ws[b]);                       // recover index (stored inverted)
  nn[t] = q[(size_t)qidx * DIM + d];
  if (t == 0) *ptr_out = (float)(((*ptr_in) + HALFB) & (QSIZE - 1));
}

extern "C" void kernel_launch(void* const* d_in, const int* in_sizes, int n_in,
                              void* d_out, int out_size, void* d_ws, size_t ws_size,
                              hipStream_t stream)
{
  const float* x   = (const float*)d_in[0];
  const float* qx  = (const float*)d_in[1];
  const int*   ptr = (const int*)d_in[2];

  float* out  = (float*)d_out;
  float* nn   = out;                         // [2048*64]
  float* newq = out + BATCH * DIM;           // [131072*64]
  float* nptr = out + BATCH * DIM + (size_t)QSIZE * DIM;  // scalar

  u64* ws = (u64*)d_ws;  // 2048 packed (sim, ~idx) slots

  hipMemsetAsync(ws, 0, BATCH * sizeof(u64), stream);

  dim3 grid(BATCH / BM, NSPLIT);
  sim_argmax_kernel<<<grid, 256, 0, stream>>>(x, qx, ws);

  int copy_f4 = QSIZE * DIM / 4;
  copy_update_kernel<<<copy_f4 / 256, 256, 0, stream>>>(x, qx, ptr, newq);

  gather_kernel<<<(BATCH * DIM) / 256, 256, 0, stream>>>(qx, ws, ptr, nn, nptr);
}

// Round 2
// 208.388 us; speedup vs baseline: 2.6421x; 2.6421x over previous
//
#include <hip/hip_runtime.h>

typedef unsigned long long u64;
typedef unsigned int u32;
typedef unsigned short u16;

#define BATCH 2048
#define DIM   64
#define QSIZE 131072
#define HALFB 1024

#define BM 128
#define BN 128
#define NTILES (QSIZE / BN)   // 1024
#define NSPLIT 64             // each block handles NTILES/NSPLIT = 16 n-tiles

#define ROWB  136             // padded LDS row: 64 bf16 data + 4 pad = 68 bf16 = 136 B
#define PLANE (BN * ROWB)     // 17408 B per plane (hi / lo)

typedef __attribute__((ext_vector_type(8)))  short short8;
typedef __attribute__((ext_vector_type(4)))  short short4v;
typedef __attribute__((ext_vector_type(16))) float f32x16;

__device__ __forceinline__ u16 bf16rn(float f) {
  u32 b = __float_as_uint(f);
  return (u16)((b + 0x7FFFu + ((b >> 16) & 1u)) >> 16);
}
__device__ __forceinline__ float bf16tof(u16 h) {
  return __uint_as_float(((u32)h) << 16);
}

// sim = x . q^T via 3-pass bf16 hi/lo MFMA (xh*qh + xl*qh + xh*ql), fused row-argmax.
// Block: 128x128 output tile. 4 waves in 2x2: wave covers 64 rows x 64 cols
// (2x2 subtiles of 32x32). A fragments persistent in registers; q tile converted
// fp32->bf16 hi/lo during LDS staging each tile.
__global__ __launch_bounds__(256, 2) void sim_argmax_kernel(
    const float* __restrict__ x, const float* __restrict__ q,
    u64* __restrict__ ws)
{
  __shared__ u64 smem8[8192];   // 64 KB: staging planes (34816 B) / reduce table (64 KB)
  char* smem = (char*)smem8;

  const int tid  = threadIdx.x;
  const int lane = tid & 63;
  const int wave = tid >> 6;
  const int wm   = wave & 1;    // m-half of the 128-tile
  const int wn   = wave >> 1;   // n-half
  const int l31  = lane & 31;
  const int lh   = lane >> 5;   // k-half within fragment
  const int mblk = blockIdx.x * BM;

  // --- persistent A fragments: ah/al[msub][ktile], layout A[m=l31][k=lh*8+j] ---
  short8 ah[2][4], al[2][4];
#pragma unroll
  for (int ms = 0; ms < 2; ++ms) {
    const float* xr = x + (size_t)(mblk + wm * 64 + ms * 32 + l31) * DIM;
#pragma unroll
    for (int kt = 0; kt < 4; ++kt) {
      const float* p = xr + kt * 16 + lh * 8;
      float4 v0 = *(const float4*)(p);
      float4 v1 = *(const float4*)(p + 4);
      float vv[8] = {v0.x, v0.y, v0.z, v0.w, v1.x, v1.y, v1.z, v1.w};
      short8 h, l;
#pragma unroll
      for (int i = 0; i < 8; ++i) {
        u16 hb = bf16rn(vv[i]);
        u16 lb = bf16rn(vv[i] - bf16tof(hb));
        h[i] = (short)hb;
        l[i] = (short)lb;
      }
      ah[ms][kt] = h;
      al[ms][kt] = l;
    }
  }

  float best[2][16];
  u32   bidx[2][16];
#pragma unroll
  for (int ms = 0; ms < 2; ++ms)
#pragma unroll
    for (int r = 0; r < 16; ++r) { best[ms][r] = -3.0e38f; bidx[ms][r] = 0; }

  for (int nt = blockIdx.y; nt < NTILES; nt += NSPLIT) {
    const int nbase = nt * BN;
    __syncthreads();  // previous tile's fragment reads complete

    // Stage q tile: read fp32 coalesced, convert to bf16 hi/lo, write padded LDS rows.
#pragma unroll
    for (int p = 0; p < 8; ++p) {
      int idx = p * 256 + tid;      // float4 chunk id, 2048 total
      int row = idx >> 4;           // 0..127
      int c   = idx & 15;           // float4 within row
      float4 v = ((const float4*)(q + (size_t)(nbase + row) * DIM))[c];
      float vv[4] = {v.x, v.y, v.z, v.w};
      short4v hv, lv;
#pragma unroll
      for (int i = 0; i < 4; ++i) {
        u16 hb = bf16rn(vv[i]);
        u16 lb = bf16rn(vv[i] - bf16tof(hb));
        hv[i] = (short)hb;
        lv[i] = (short)lb;
      }
      *(short4v*)(smem + row * ROWB + c * 8)         = hv;
      *(short4v*)(smem + PLANE + row * ROWB + c * 8) = lv;
    }
    __syncthreads();

#pragma unroll
    for (int ns = 0; ns < 2; ++ns) {
      // B fragments for this n-subtile: B[n=l31][k=lh*8+j], rows padded 136 B -> b64 pairs, 2-way free
      short8 bh[4], bl[4];
      const int brow = wn * 64 + ns * 32 + l31;
#pragma unroll
      for (int kt = 0; kt < 4; ++kt) {
        const int off = brow * ROWB + kt * 32 + lh * 16;
        union { short8 v; short4v h[2]; } fh, fl;
        fh.h[0] = *(const short4v*)(smem + off);
        fh.h[1] = *(const short4v*)(smem + off + 8);
        fl.h[0] = *(const short4v*)(smem + PLANE + off);
        fl.h[1] = *(const short4v*)(smem + PLANE + off + 8);
        bh[kt] = fh.v;
        bl[kt] = fl.v;
      }
      const u32 col = (u32)(nbase + wn * 64 + ns * 32 + l31);

#pragma unroll
      for (int ms = 0; ms < 2; ++ms) {
        f32x16 acc;
#pragma unroll
        for (int i = 0; i < 16; ++i) acc[i] = 0.0f;
#pragma unroll
        for (int kt = 0; kt < 4; ++kt) {
          acc = __builtin_amdgcn_mfma_f32_32x32x16_bf16(ah[ms][kt], bh[kt], acc, 0, 0, 0);
          acc = __builtin_amdgcn_mfma_f32_32x32x16_bf16(al[ms][kt], bh[kt], acc, 0, 0, 0);
          acc = __builtin_amdgcn_mfma_f32_32x32x16_bf16(ah[ms][kt], bl[kt], acc, 0, 0, 0);
        }
        // n scans ascending (tiles asc, ns asc), strict '>' -> smallest index wins ties.
#pragma unroll
        for (int r = 0; r < 16; ++r) {
          if (acc[r] > best[ms][r]) { best[ms][r] = acc[r]; bidx[ms][r] = col; }
        }
      }
    }
  }

  // --- block reduce: table[row 0..127][colclass 0..63], packed (monotone key | ~idx) ---
  __syncthreads();
  u64* table = smem8;
#pragma unroll
  for (int ms = 0; ms < 2; ++ms)
#pragma unroll
    for (int r = 0; r < 16; ++r) {
      int row = wm * 64 + ms * 32 + (r & 3) + 8 * (r >> 2) + 4 * lh;
      u32 fb = __float_as_uint(best[ms][r]);
      fb = (fb & 0x80000000u) ? ~fb : (fb | 0x80000000u);
      table[row * 64 + wn * 32 + l31] = ((u64)fb << 32) | (u32)(~bidx[ms][r]);
    }
  __syncthreads();
  if (tid < BM) {
    u64 mx = 0;
    for (int j = 0; j < 64; ++j) {
      u64 v = table[tid * 64 + j];
      mx = (v > mx) ? v : mx;
    }
    atomicMax(&ws[mblk + tid], mx);
  }
}

// new_queue: copy queue, substituting rows [ptr, ptr+1024) mod SIZE from x.
__global__ void copy_update_kernel(const float* __restrict__ x,
                                   const float* __restrict__ q,
                                   const int* __restrict__ ptr_in,
                                   float* __restrict__ newq)
{
  int i = blockIdx.x * blockDim.x + threadIdx.x;  // float4 index
  int r = i >> 4;
  int c = i & 15;
  int ptr = *ptr_in;
  u32 off = (u32)(r - ptr) & (QSIZE - 1);
  float4 v = (off < HALFB) ? ((const float4*)x)[off * 16 + c]
                           : ((const float4*)q)[i];
  ((float4*)newq)[i] = v;
}

__global__ void gather_kernel(const float* __restrict__ q,
                              const u64* __restrict__ ws,
                              const int* __restrict__ ptr_in,
                              float* __restrict__ nn,
                              float* __restrict__ ptr_out)
{
  int t = blockIdx.x * blockDim.x + threadIdx.x;
  int b = t >> 6;
  int d = t & 63;
  u32 qidx = ~(u32)(ws[b]);
  nn[t] = q[(size_t)qidx * DIM + d];
  if (t == 0) *ptr_out = (float)(((*ptr_in) + HALFB) & (QSIZE - 1));
}

extern "C" void kernel_launch(void* const* d_in, const int* in_sizes, int n_in,
                              void* d_out, int out_size, void* d_ws, size_t ws_size,
                              hipStream_t stream)
{
  const float* x   = (const float*)d_in[0];
  const float* qx  = (const float*)d_in[1];
  const int*   ptr = (const int*)d_in[2];

  float* out  = (float*)d_out;
  float* nn   = out;
  float* newq = out + BATCH * DIM;
  float* nptr = out + BATCH * DIM + (size_t)QSIZE * DIM;

  u64* ws = (u64*)d_ws;  // 2048 packed (sim, ~idx) slots = 16 KB

  hipMemsetAsync(ws, 0, BATCH * sizeof(u64), stream);

  dim3 grid(BATCH / BM, NSPLIT);
  sim_argmax_kernel<<<grid, 256, 0, stream>>>(x, qx, ws);

  int copy_f4 = QSIZE * DIM / 4;
  copy_update_kernel<<<copy_f4 / 256, 256, 0, stream>>>(x, qx, ptr, newq);

  gather_kernel<<<(BATCH * DIM) / 256, 256, 0, stream>>>(qx, ws, ptr, nn, nptr);
}

// Round 3
// 202.354 us; speedup vs baseline: 2.7209x; 1.0298x over previous
//
#include <hip/hip_runtime.h>

typedef unsigned long long u64;
typedef unsigned int u32;
typedef unsigned short u16;

#define BATCH 2048
#define DIM   64
#define QSIZE 131072
#define HALFB 1024

#define BM 128
#define BN 256
#define NTILES (QSIZE / BN)              // 512
#define NSPLIT 64                        // tiles per block = 8
#define ROWB   128                       // bytes per bf16 row (64 * 2)
#define PLANEG ((size_t)QSIZE * ROWB)    // 16 MiB per global plane (hi / lo)
#define PLANEL (BN * ROWB)               // 32 KiB per LDS plane

typedef __attribute__((ext_vector_type(8)))  short short8;
typedef __attribute__((ext_vector_type(4)))  short short4v;
typedef __attribute__((ext_vector_type(16))) float f32x16;

__device__ __forceinline__ u16 bf16rn(float f) {
  u32 b = __float_as_uint(f);
  return (u16)((b + 0x7FFFu + ((b >> 16) & 1u)) >> 16);
}
__device__ __forceinline__ float bf16tof(u16 h) {
  return __uint_as_float(((u32)h) << 16);
}

__device__ __forceinline__ void gload_lds16(const void* g, void* l) {
  __builtin_amdgcn_global_load_lds(
      (__attribute__((address_space(1))) void*)(g),
      (__attribute__((address_space(3))) void*)(l),
      16, 0, 0);
}

// Pre-convert q fp32 -> bf16 hi/lo planes, XOR-swizzled (chunk ^ (row&7)) so the
// sim kernel's global_load_lds staging lands bank-uniform in LDS without padding.
// Also zeroes the 2048 argmax slots (replaces hipMemsetAsync).
__global__ void preconv_kernel(const float* __restrict__ q, char* __restrict__ qc,
                               u64* __restrict__ ws)
{
  int i = blockIdx.x * 256 + threadIdx.x;   // float4 id, QSIZE*16 total
  if (i < BATCH) ws[i] = 0;
  int row = i >> 4;
  int c4  = i & 15;
  float4 v = ((const float4*)q)[i];
  float vv[4] = {v.x, v.y, v.z, v.w};
  short4v hv, lv;
#pragma unroll
  for (int k = 0; k < 4; ++k) {
    u16 hb = bf16rn(vv[k]);
    u16 lb = bf16rn(vv[k] - bf16tof(hb));
    hv[k] = (short)hb;
    lv[k] = (short)lb;
  }
  int chunk = c4 >> 1, half = c4 & 1;
  int phys  = chunk ^ (row & 7);
  size_t off = (size_t)row * ROWB + phys * 16 + half * 8;
  *(short4v*)(qc + off)          = hv;
  *(short4v*)(qc + PLANEG + off) = lv;
}

// sim = x . q^T via 3-pass bf16 hi/lo MFMA, fused row-argmax.
// 128x256 tile/block; 4 waves 2x2; A persistent in regs; B staged via
// global_load_lds (16B) from the pre-swizzled bf16 planes.
__global__ __launch_bounds__(256, 2) void sim_argmax_kernel(
    const float* __restrict__ x, const char* __restrict__ qc,
    u64* __restrict__ ws)
{
  __shared__ char smem[2 * PLANEL];   // 64 KB

  const int tid  = threadIdx.x;
  const int lane = tid & 63;
  const int wave = tid >> 6;
  const int wm   = wave & 1;    // m-half
  const int wn   = wave >> 1;   // n-half
  const int l31  = lane & 31;
  const int lh   = lane >> 5;
  const int mblk = blockIdx.x * BM;

  // persistent A fragments: A[m=l31][k=lh*8+j]
  short8 ah[2][4], al[2][4];
#pragma unroll
  for (int ms = 0; ms < 2; ++ms) {
    const float* xr = x + (size_t)(mblk + wm * 64 + ms * 32 + l31) * DIM;
#pragma unroll
    for (int kt = 0; kt < 4; ++kt) {
      const float* p = xr + kt * 16 + lh * 8;
      float4 v0 = *(const float4*)(p);
      float4 v1 = *(const float4*)(p + 4);
      float vv[8] = {v0.x, v0.y, v0.z, v0.w, v1.x, v1.y, v1.z, v1.w};
      short8 h, l;
#pragma unroll
      for (int i = 0; i < 8; ++i) {
        u16 hb = bf16rn(vv[i]);
        u16 lb = bf16rn(vv[i] - bf16tof(hb));
        h[i] = (short)hb;
        l[i] = (short)lb;
      }
      ah[ms][kt] = h;
      al[ms][kt] = l;
    }
  }

  float best[2][16];
  u32   bidx[2][16];
#pragma unroll
  for (int ms = 0; ms < 2; ++ms)
#pragma unroll
    for (int r = 0; r < 16; ++r) { best[ms][r] = -3.0e38f; bidx[ms][r] = 0; }

  char* lbase = smem + wave * 1024;   // wave-uniform LDS staging base

  for (int it = 0; it < NTILES / NSPLIT; ++it) {
    const int nt = blockIdx.y + it * NSPLIT;
    const size_t tileoff = (size_t)nt * BN * ROWB;
    __syncthreads();   // prior tile's fragment reads complete
    const char* shi = qc + tileoff + wave * 1024 + lane * 16;
    const char* slo = shi + PLANEG;
#pragma unroll
    for (int p = 0; p < 8; ++p) gload_lds16(shi + p * 4096, lbase + p * 4096);
#pragma unroll
    for (int p = 0; p < 8; ++p) gload_lds16(slo + p * 4096, lbase + PLANEL + p * 4096);
    __syncthreads();   // compiler drains vmcnt before barrier -> DMA complete

#pragma unroll
    for (int ns = 0; ns < 4; ++ns) {
      const int brow = wn * 128 + ns * 32 + l31;
      const int sw   = brow & 7;
      short8 bh[4], bl[4];
#pragma unroll
      for (int kt = 0; kt < 4; ++kt) {
        int off = brow * ROWB + (((kt * 2 + lh) ^ sw) << 4);
        bh[kt] = *(const short8*)(smem + off);
        bl[kt] = *(const short8*)(smem + PLANEL + off);
      }
      const u32 col = (u32)(nt * BN + wn * 128 + ns * 32 + l31);

#pragma unroll
      for (int ms = 0; ms < 2; ++ms) {
        f32x16 acc;
#pragma unroll
        for (int i = 0; i < 16; ++i) acc[i] = 0.0f;
#pragma unroll
        for (int kt = 0; kt < 4; ++kt) {
          acc = __builtin_amdgcn_mfma_f32_32x32x16_bf16(ah[ms][kt], bh[kt], acc, 0, 0, 0);
          acc = __builtin_amdgcn_mfma_f32_32x32x16_bf16(al[ms][kt], bh[kt], acc, 0, 0, 0);
          acc = __builtin_amdgcn_mfma_f32_32x32x16_bf16(ah[ms][kt], bl[kt], acc, 0, 0, 0);
        }
        // col scans ascending (it asc, ns asc); strict '>' keeps smallest index.
#pragma unroll
        for (int r = 0; r < 16; ++r) {
          if (acc[r] > best[ms][r]) { best[ms][r] = acc[r]; bidx[ms][r] = col; }
        }
      }
    }
  }

  // block reduce: table[row 0..127][l31 0..31], two wn phases, then 128-thread scan
  __syncthreads();
  u64* table = (u64*)smem;   // 32 KB, aliases staging
  if (wn == 0) {
#pragma unroll
    for (int ms = 0; ms < 2; ++ms)
#pragma unroll
      for (int r = 0; r < 16; ++r) {
        int row = wm * 64 + ms * 32 + (r & 3) + 8 * (r >> 2) + 4 * lh;
        u32 fb = __float_as_uint(best[ms][r]);
        fb = (fb & 0x80000000u) ? ~fb : (fb | 0x80000000u);
        table[row * 32 + l31] = ((u64)fb << 32) | (u32)(~bidx[ms][r]);
      }
  }
  __syncthreads();
  if (wn == 1) {
#pragma unroll
    for (int ms = 0; ms < 2; ++ms)
#pragma unroll
      for (int r = 0; r < 16; ++r) {
        int row = wm * 64 + ms * 32 + (r & 3) + 8 * (r >> 2) + 4 * lh;
        u32 fb = __float_as_uint(best[ms][r]);
        fb = (fb & 0x80000000u) ? ~fb : (fb | 0x80000000u);
        u64 pk = ((u64)fb << 32) | (u32)(~bidx[ms][r]);
        u64* slot = &table[row * 32 + l31];
        if (pk > *slot) *slot = pk;   // unique writer per slot in this phase
      }
  }
  __syncthreads();
  if (tid < BM) {
    u64 mx = 0;
    for (int j = 0; j < 32; ++j) {
      u64 v = table[tid * 32 + j];
      mx = (v > mx) ? v : mx;
    }
    atomicMax(&ws[mblk + tid], mx);
  }
}

// Fused tail: new_queue copy-with-substitution (blocks 0..8191), nn gather +
// ptr (blocks 8192..8703). Runs after sim; overwrites the qconv scratch region.
__global__ void finish_kernel(const float* __restrict__ x, const float* __restrict__ q,
                              const int* __restrict__ ptr_in, const u64* __restrict__ ws,
                              float* __restrict__ nn, float* __restrict__ newq,
                              float* __restrict__ nptr)
{
  int bid = blockIdx.x;
  if (bid < 8192) {
    int i = bid * 256 + threadIdx.x;   // float4 index
    int r = i >> 4;
    int c = i & 15;
    int ptr = *ptr_in;
    u32 off = (u32)(r - ptr) & (QSIZE - 1);
    float4 v = (off < HALFB) ? ((const float4*)x)[off * 16 + c]
                             : ((const float4*)q)[i];
    ((float4*)newq)[i] = v;
  } else {
    int t = (bid - 8192) * 256 + threadIdx.x;  // 0 .. BATCH*DIM-1
    int b = t >> 6;
    int d = t & 63;
    u32 qidx = ~(u32)(ws[b]);
    nn[t] = q[(size_t)qidx * DIM + d];
    if (t == 0) *nptr = (float)(((*ptr_in) + HALFB) & (QSIZE - 1));
  }
}

extern "C" void kernel_launch(void* const* d_in, const int* in_sizes, int n_in,
                              void* d_out, int out_size, void* d_ws, size_t ws_size,
                              hipStream_t stream)
{
  const float* x   = (const float*)d_in[0];
  const float* qx  = (const float*)d_in[1];
  const int*   ptr = (const int*)d_in[2];

  float* out  = (float*)d_out;
  float* nn   = out;
  float* newq = out + BATCH * DIM;
  float* nptr = out + BATCH * DIM + (size_t)QSIZE * DIM;

  char* qc = (char*)newq;   // 32 MB bf16 hi/lo scratch inside the newq slot
  u64*  ws = (u64*)d_ws;    // 2048 packed (sim, ~idx) slots

  preconv_kernel<<<QSIZE * 16 / 256, 256, 0, stream>>>(qx, qc, ws);

  dim3 grid(BATCH / BM, NSPLIT);
  sim_argmax_kernel<<<grid, 256, 0, stream>>>(x, qc, ws);

  finish_kernel<<<8192 + (BATCH * DIM) / 256, 256, 0, stream>>>(
      x, qx, ptr, ws, nn, newq, nptr);
}